// Round 1
// baseline (1697.079 us; speedup 1.0000x reference)
//
#include <hip/hip_runtime.h>

#define D 128

// Order-preserving float<->uint mapping for atomicMax on floats.
__device__ __forceinline__ unsigned f2ord(float f) {
  unsigned b = __float_as_uint(f);
  return (b & 0x80000000u) ? ~b : (b | 0x80000000u);
}
__device__ __forceinline__ float ord2f(unsigned u) {
  unsigned b = (u & 0x80000000u) ? (u & 0x7fffffffu) : ~u;
  return __uint_as_float(b);
}

// K1: keys_proj[m][j] = sum_k attn_keys[m][k] * W[j][k] + b[j]
// Tile: 32 rows x 128 cols per block of 256 threads; thread computes 4x4.
__global__ __launch_bounds__(256) void k_keys_proj(
    const float* __restrict__ attn_keys, const float* __restrict__ W,
    const float* __restrict__ b, float* __restrict__ keys_proj, int M) {
  __shared__ float sKey[32][D + 1];  // [row][k], pad -> conflict-free stage
  __shared__ float sWt[32][D + 1];   // [k_local][j], (k+j)%32 banks on stage
  const int tid = threadIdx.x;
  const int tc = tid & 31;   // cols 4*tc .. 4*tc+3
  const int tr = tid >> 5;   // rows 4*tr .. 4*tr+3
  const int row0 = blockIdx.x * 32;

  for (int e = tid; e < 32 * D; e += 256) {
    int r = e >> 7, k = e & (D - 1);
    int row = row0 + r;
    sKey[r][k] = (row < M) ? attn_keys[(size_t)row * D + k] : 0.0f;
  }

  float acc[4][4];
#pragma unroll
  for (int i = 0; i < 4; ++i)
#pragma unroll
    for (int c = 0; c < 4; ++c) acc[i][c] = 0.0f;

  for (int kc = 0; kc < D; kc += 32) {
    __syncthreads();  // covers sKey stage (first iter) / prev-chunk reads
    for (int e = tid; e < 32 * D; e += 256) {
      int k = e & 31, j = e >> 5;
      sWt[k][j] = W[(size_t)j * D + kc + k];
    }
    __syncthreads();
#pragma unroll 8
    for (int kk = 0; kk < 32; ++kk) {
      float kv[4], wv[4];
#pragma unroll
      for (int i = 0; i < 4; ++i) kv[i] = sKey[4 * tr + i][kc + kk];  // broadcast
#pragma unroll
      for (int c = 0; c < 4; ++c) wv[c] = sWt[kk][4 * tc + c];
#pragma unroll
      for (int i = 0; i < 4; ++i)
#pragma unroll
        for (int c = 0; c < 4; ++c) acc[i][c] += kv[i] * wv[c];
    }
  }

#pragma unroll
  for (int i = 0; i < 4; ++i) {
    int row = row0 + 4 * tr + i;
    if (row < M) {
#pragma unroll
      for (int c = 0; c < 4; ++c) {
        int j = 4 * tc + c;
        keys_proj[(size_t)row * D + j] = acc[i][c] + b[j];
      }
    }
  }
}

// K2: probs[i] = dot(values[i], keys_proj[idx[i]]); atomic segment max.
// One wave (64 lanes) per row; lane handles a float2 (128 floats/row).
__global__ __launch_bounds__(256) void k_probs(
    const float* __restrict__ values, const int* __restrict__ indices,
    const float* __restrict__ keys_proj, float* __restrict__ probs,
    unsigned* __restrict__ seg_max, int N) {
  const int lane = threadIdx.x & 63;
  const int wid = (int)((blockIdx.x * blockDim.x + threadIdx.x) >> 6);
  const int nw = (int)((gridDim.x * blockDim.x) >> 6);
  for (int i = wid; i < N; i += nw) {
    const int m = indices[i];
    const float2 v = ((const float2*)(values + (size_t)i * D))[lane];
    const float2 k = ((const float2*)(keys_proj + (size_t)m * D))[lane];
    float s = v.x * k.x + v.y * k.y;
#pragma unroll
    for (int off = 32; off > 0; off >>= 1) s += __shfl_xor(s, off, 64);
    if (lane == 0) {
      probs[i] = s;
      atomicMax(seg_max + m, f2ord(s));
    }
  }
}

// K3: ex = exp(p - segmax) stored in-place; atomic segment sum.
__global__ __launch_bounds__(256) void k_exp(
    const int* __restrict__ indices, float* __restrict__ probs,
    const unsigned* __restrict__ seg_max, float* __restrict__ seg_sum, int N) {
  int i = blockIdx.x * blockDim.x + threadIdx.x;
  const int stride = gridDim.x * blockDim.x;
  for (; i < N; i += stride) {
    const int m = indices[i];
    const float e = __expf(probs[i] - ord2f(seg_max[m]));
    probs[i] = e;
    atomicAdd(seg_sum + m, e);
  }
}

// K4: scores out + scatter-accumulate score-weighted values into attn_out.
__global__ __launch_bounds__(256) void k_scatter(
    const float* __restrict__ values, const int* __restrict__ indices,
    const float* __restrict__ ex, const float* __restrict__ seg_sum,
    float* __restrict__ scores, float* __restrict__ attn_out, int N) {
  const int lane = threadIdx.x & 63;
  const int wid = (int)((blockIdx.x * blockDim.x + threadIdx.x) >> 6);
  const int nw = (int)((gridDim.x * blockDim.x) >> 6);
  for (int i = wid; i < N; i += nw) {
    const int m = indices[i];
    const float s = ex[i] / seg_sum[m];
    if (lane == 0) scores[i] = s;
    const float2 v = ((const float2*)(values + (size_t)i * D))[lane];
    float* dst = attn_out + (size_t)m * D + lane * 2;
    atomicAdd(dst, v.x * s);
    atomicAdd(dst + 1, v.y * s);
  }
}

extern "C" void kernel_launch(void* const* d_in, const int* in_sizes, int n_in,
                              void* d_out, int out_size, void* d_ws, size_t ws_size,
                              hipStream_t stream) {
  const float* values = (const float*)d_in[0];
  const int* indices = (const int*)d_in[1];
  const float* attn_keys = (const float*)d_in[2];
  const float* W = (const float*)d_in[3];
  const float* b = (const float*)d_in[4];
  const int N = in_sizes[0] / D;  // 1,000,000
  const int M = in_sizes[2] / D;  // 50,000

  // Workspace layout (floats): keys_proj [M*D] | probs [N] | seg_max [M] | seg_sum [M]
  float* keys_proj = (float*)d_ws;
  float* probs = keys_proj + (size_t)M * D;
  unsigned* seg_max = (unsigned*)(probs + N);
  float* seg_sum = (float*)(seg_max + M);

  float* scores = (float*)d_out;
  float* attn_out = scores + N;

  // Zero accumulators (ws/d_out are poisoned 0xAA before every launch).
  // seg_max sentinel 0 is below f2ord of any real float.
  hipMemsetAsync(seg_max, 0, (size_t)M * 2 * sizeof(unsigned), stream);
  hipMemsetAsync(attn_out, 0, (size_t)M * D * sizeof(float), stream);

  k_keys_proj<<<(M + 31) / 32, 256, 0, stream>>>(attn_keys, W, b, keys_proj, M);
  k_probs<<<8192, 256, 0, stream>>>(values, indices, keys_proj, probs, seg_max, N);
  k_exp<<<2048, 256, 0, stream>>>(indices, probs, seg_max, seg_sum, N);
  k_scatter<<<8192, 256, 0, stream>>>(values, indices, probs, seg_sum, scores, attn_out, N);
}

// Round 2
// 997.549 us; speedup vs baseline: 1.7012x; 1.7012x over previous
//
#include <hip/hip_runtime.h>
#include <float.h>

#define D 128

// ---------------------------------------------------------------------------
// K1: keys_proj[m][j] = sum_k attn_keys[m][k] * W[j][k] + b[j]   (unchanged)
// ---------------------------------------------------------------------------
__global__ __launch_bounds__(256) void k_keys_proj(
    const float* __restrict__ attn_keys, const float* __restrict__ W,
    const float* __restrict__ b, float* __restrict__ keys_proj, int M) {
  __shared__ float sKey[32][D + 1];
  __shared__ float sWt[32][D + 1];
  const int tid = threadIdx.x;
  const int tc = tid & 31;
  const int tr = tid >> 5;
  const int row0 = blockIdx.x * 32;

  for (int e = tid; e < 32 * D; e += 256) {
    int r = e >> 7, k = e & (D - 1);
    int row = row0 + r;
    sKey[r][k] = (row < M) ? attn_keys[(size_t)row * D + k] : 0.0f;
  }

  float acc[4][4];
#pragma unroll
  for (int i = 0; i < 4; ++i)
#pragma unroll
    for (int c = 0; c < 4; ++c) acc[i][c] = 0.0f;

  for (int kc = 0; kc < D; kc += 32) {
    __syncthreads();
    for (int e = tid; e < 32 * D; e += 256) {
      int k = e & 31, j = e >> 5;
      sWt[k][j] = W[(size_t)j * D + kc + k];
    }
    __syncthreads();
#pragma unroll 8
    for (int kk = 0; kk < 32; ++kk) {
      float kv[4], wv[4];
#pragma unroll
      for (int i = 0; i < 4; ++i) kv[i] = sKey[4 * tr + i][kc + kk];
#pragma unroll
      for (int c = 0; c < 4; ++c) wv[c] = sWt[kk][4 * tc + c];
#pragma unroll
      for (int i = 0; i < 4; ++i)
#pragma unroll
        for (int c = 0; c < 4; ++c) acc[i][c] += kv[i] * wv[c];
    }
  }

#pragma unroll
  for (int i = 0; i < 4; ++i) {
    int row = row0 + 4 * tr + i;
    if (row < M) {
#pragma unroll
      for (int c = 0; c < 4; ++c) {
        int j = 4 * tc + c;
        keys_proj[(size_t)row * D + j] = acc[i][c] + b[j];
      }
    }
  }
}

// ---------------------------------------------------------------------------
// CSR build: counts -> offsets (atomic cursor; any disjoint layout is valid)
//            -> fill row lists
// ---------------------------------------------------------------------------
__global__ __launch_bounds__(256) void k_count(
    const int* __restrict__ indices, int* __restrict__ counts, int N) {
  int i = blockIdx.x * blockDim.x + threadIdx.x;
  const int stride = gridDim.x * blockDim.x;
  for (; i < N; i += stride) atomicAdd(counts + indices[i], 1);
}

__global__ __launch_bounds__(256) void k_offsets(
    const int* __restrict__ counts, int* __restrict__ fillpos,
    int* __restrict__ cursor, int M) {
  int m = blockIdx.x * blockDim.x + threadIdx.x;
  if (m < M) fillpos[m] = atomicAdd(cursor, counts[m]);
}

__global__ __launch_bounds__(256) void k_fill(
    const int* __restrict__ indices, int* __restrict__ fillpos,
    int* __restrict__ rowids, int N) {
  int i = blockIdx.x * blockDim.x + threadIdx.x;
  const int stride = gridDim.x * blockDim.x;
  for (; i < N; i += stride) {
    int p = atomicAdd(fillpos + indices[i], 1);
    rowids[p] = i;
  }
}

// ---------------------------------------------------------------------------
// K5: one wave per segment, flash-style online softmax + weighted accumulate.
// Values read ONCE. keys_proj row lives in registers. After the loop,
// fillpos[m] == end of segment m; start = end - counts[m].
// Raw dot s_i is stashed into scores[i] (d_out), normalized by K6.
// ---------------------------------------------------------------------------
__global__ __launch_bounds__(256) void k_segment(
    const float* __restrict__ values, const int* __restrict__ rowids,
    const int* __restrict__ counts, const int* __restrict__ fillpos,
    const float* __restrict__ keys_proj, float* __restrict__ raw_scores,
    float* __restrict__ seg_m, float* __restrict__ seg_l,
    float* __restrict__ attn_out, int M) {
  const int lane = threadIdx.x & 63;
  const int wid = (int)((blockIdx.x * blockDim.x + threadIdx.x) >> 6);
  const int nw = (int)((gridDim.x * blockDim.x) >> 6);

  for (int m = wid; m < M; m += nw) {
    const int cnt = counts[m];
    const int start = fillpos[m] - cnt;
    const float2 k = ((const float2*)(keys_proj + (size_t)m * D))[lane];

    float run_m = -FLT_MAX, run_l = 0.0f;
    float2 acc = {0.0f, 0.0f};

    // one-ahead software prefetch of rowid + value row
    int i_next = 0;
    float2 v_next = {0.0f, 0.0f};
    if (cnt > 0) {
      i_next = rowids[start];
      v_next = ((const float2*)(values + (size_t)i_next * D))[lane];
    }

    for (int r = 0; r < cnt; ++r) {
      const int i = i_next;
      const float2 v = v_next;
      if (r + 1 < cnt) {
        i_next = rowids[start + r + 1];
        v_next = ((const float2*)(values + (size_t)i_next * D))[lane];
      }
      float s = v.x * k.x + v.y * k.y;
#pragma unroll
      for (int off = 32; off > 0; off >>= 1) s += __shfl_xor(s, off, 64);
      if (lane == 0) raw_scores[i] = s;
      const float mn = fmaxf(run_m, s);
      const float alpha = __expf(run_m - mn);  // 0 on first iter (exp(-inf))
      const float p = __expf(s - mn);
      run_l = run_l * alpha + p;
      acc.x = acc.x * alpha + p * v.x;
      acc.y = acc.y * alpha + p * v.y;
      run_m = mn;
    }

    const float inv = (cnt > 0) ? 1.0f / run_l : 0.0f;
    float2 out = {acc.x * inv, acc.y * inv};
    ((float2*)(attn_out + (size_t)m * D))[lane] = out;
    if (lane == 0) {
      seg_m[m] = run_m;
      seg_l[m] = run_l;
    }
  }
}

// ---------------------------------------------------------------------------
// K6: normalize raw dots into final scores, in place in d_out.
// ---------------------------------------------------------------------------
__global__ __launch_bounds__(256) void k_scores(
    const int* __restrict__ indices, const float* __restrict__ seg_m,
    const float* __restrict__ seg_l, float* __restrict__ scores, int N) {
  int i = blockIdx.x * blockDim.x + threadIdx.x;
  const int stride = gridDim.x * blockDim.x;
  for (; i < N; i += stride) {
    const int m = indices[i];
    scores[i] = __expf(scores[i] - seg_m[m]) / seg_l[m];
  }
}

extern "C" void kernel_launch(void* const* d_in, const int* in_sizes, int n_in,
                              void* d_out, int out_size, void* d_ws, size_t ws_size,
                              hipStream_t stream) {
  const float* values = (const float*)d_in[0];
  const int* indices = (const int*)d_in[1];
  const float* attn_keys = (const float*)d_in[2];
  const float* W = (const float*)d_in[3];
  const float* b = (const float*)d_in[4];
  const int N = in_sizes[0] / D;  // 1,000,000
  const int M = in_sizes[2] / D;  // 50,000

  // Workspace layout:
  //   keys_proj [M*D] f32 | counts [M] i32 | fillpos [M] i32 |
  //   seg_m [M] f32 | seg_l [M] f32 | cursor [64] i32 | rowids [N] i32
  float* keys_proj = (float*)d_ws;
  int* counts = (int*)(keys_proj + (size_t)M * D);
  int* fillpos = counts + M;
  float* seg_mv = (float*)(fillpos + M);
  float* seg_lv = seg_mv + M;
  int* cursor = (int*)(seg_lv + M);
  int* rowids = cursor + 64;

  float* scores = (float*)d_out;       // raw dots, then normalized in place
  float* attn_out = scores + N;

  // Zero counts + cursor (ws is poisoned 0xAA before every launch).
  hipMemsetAsync(counts, 0, (size_t)M * sizeof(int), stream);
  hipMemsetAsync(cursor, 0, 64 * sizeof(int), stream);

  k_keys_proj<<<(M + 31) / 32, 256, 0, stream>>>(attn_keys, W, b, keys_proj, M);
  k_count<<<1024, 256, 0, stream>>>(indices, counts, N);
  k_offsets<<<(M + 255) / 256, 256, 0, stream>>>(counts, fillpos, cursor, M);
  k_fill<<<1024, 256, 0, stream>>>(indices, fillpos, rowids, N);
  k_segment<<<2048, 256, 0, stream>>>(values, rowids, counts, fillpos, keys_proj,
                                      scores, seg_mv, seg_lv, attn_out, M);
  k_scores<<<1024, 256, 0, stream>>>(indices, seg_mv, seg_lv, scores, N);
}

// Round 3
// 892.868 us; speedup vs baseline: 1.9007x; 1.1172x over previous
//
#include <hip/hip_runtime.h>
#include <float.h>

#define D 128
#define CAP 512  // per-wave LDS score stash (counts ~Poisson(20); overflow -> global)

// ---------------------------------------------------------------------------
// K1: keys_proj[m][j] = sum_k attn_keys[m][k] * W[j][k] + b[j]
// ---------------------------------------------------------------------------
__global__ __launch_bounds__(256) void k_keys_proj(
    const float* __restrict__ attn_keys, const float* __restrict__ W,
    const float* __restrict__ b, float* __restrict__ keys_proj, int M) {
  __shared__ float sKey[32][D + 1];
  __shared__ float sWt[32][D + 1];
  const int tid = threadIdx.x;
  const int tc = tid & 31;
  const int tr = tid >> 5;
  const int row0 = blockIdx.x * 32;

  for (int e = tid; e < 32 * D; e += 256) {
    int r = e >> 7, k = e & (D - 1);
    int row = row0 + r;
    sKey[r][k] = (row < M) ? attn_keys[(size_t)row * D + k] : 0.0f;
  }

  float acc[4][4];
#pragma unroll
  for (int i = 0; i < 4; ++i)
#pragma unroll
    for (int c = 0; c < 4; ++c) acc[i][c] = 0.0f;

  for (int kc = 0; kc < D; kc += 32) {
    __syncthreads();
    for (int e = tid; e < 32 * D; e += 256) {
      int k = e & 31, j = e >> 5;
      sWt[k][j] = W[(size_t)j * D + kc + k];
    }
    __syncthreads();
#pragma unroll 8
    for (int kk = 0; kk < 32; ++kk) {
      float kv[4], wv[4];
#pragma unroll
      for (int i = 0; i < 4; ++i) kv[i] = sKey[4 * tr + i][kc + kk];
#pragma unroll
      for (int c = 0; c < 4; ++c) wv[c] = sWt[kk][4 * tc + c];
#pragma unroll
      for (int i = 0; i < 4; ++i)
#pragma unroll
        for (int c = 0; c < 4; ++c) acc[i][c] += kv[i] * wv[c];
    }
  }

#pragma unroll
  for (int i = 0; i < 4; ++i) {
    int row = row0 + 4 * tr + i;
    if (row < M) {
#pragma unroll
      for (int c = 0; c < 4; ++c) {
        int j = 4 * tc + c;
        keys_proj[(size_t)row * D + j] = acc[i][c] + b[j];
      }
    }
  }
}

// ---------------------------------------------------------------------------
// CSR build (vectorized index reads)
// ---------------------------------------------------------------------------
__global__ __launch_bounds__(256) void k_count(
    const int* __restrict__ indices, int* __restrict__ counts, int N) {
  int i = blockIdx.x * blockDim.x + threadIdx.x;
  const int stride = gridDim.x * blockDim.x;
  const int n4 = N >> 2;
  const int4* idx4 = (const int4*)indices;
  for (int j = i; j < n4; j += stride) {
    int4 v = idx4[j];
    atomicAdd(counts + v.x, 1);
    atomicAdd(counts + v.y, 1);
    atomicAdd(counts + v.z, 1);
    atomicAdd(counts + v.w, 1);
  }
  for (int j = (n4 << 2) + i; j < N; j += stride) atomicAdd(counts + indices[j], 1);
}

__global__ __launch_bounds__(256) void k_offsets(
    const int* __restrict__ counts, int* __restrict__ fillpos,
    int* __restrict__ cursor, int M) {
  int m = blockIdx.x * blockDim.x + threadIdx.x;
  if (m < M) fillpos[m] = atomicAdd(cursor, counts[m]);
}

__global__ __launch_bounds__(256) void k_fill(
    const int* __restrict__ indices, int* __restrict__ fillpos,
    int* __restrict__ rowids, int N) {
  int i = blockIdx.x * blockDim.x + threadIdx.x;
  const int stride = gridDim.x * blockDim.x;
  const int n4 = N >> 2;
  const int4* idx4 = (const int4*)indices;
  for (int j = i; j < n4; j += stride) {
    int4 v = idx4[j];
    int base = 4 * j;
    rowids[atomicAdd(fillpos + v.x, 1)] = base;
    rowids[atomicAdd(fillpos + v.y, 1)] = base + 1;
    rowids[atomicAdd(fillpos + v.z, 1)] = base + 2;
    rowids[atomicAdd(fillpos + v.w, 1)] = base + 3;
  }
  for (int j = (n4 << 2) + i; j < N; j += stride)
    rowids[atomicAdd(fillpos + indices[j], 1)] = j;
}

// ---------------------------------------------------------------------------
// K5: one wave per segment. Layout: lane = 16*g + t; row-slot g in [0,4),
// col chunk t in [0,16) covering cols 8t..8t+7. Per group of 4 rows:
// 2 gather-load instrs (2 KB), 4-step butterfly within 16 lanes, 4 broadcast
// shuffles. Online softmax state is wave-uniform. Scores finalized in-kernel
// from the LDS stash; attn row written once. After k_fill, fillpos[m] == end.
// ---------------------------------------------------------------------------
__global__ __launch_bounds__(256) void k_segment(
    const float* __restrict__ values, const int* __restrict__ rowids,
    const int* __restrict__ counts, const int* __restrict__ fillpos,
    const float* __restrict__ keys_proj, float* __restrict__ raw_ovf,
    float* __restrict__ scores, float* __restrict__ attn_out, int M) {
  __shared__ float sS[4][CAP];
  const int lane = threadIdx.x & 63;
  const int wv = threadIdx.x >> 6;
  const int m = blockIdx.x * 4 + wv;
  if (m >= M) return;
  const int g = lane >> 4;  // row slot
  const int t = lane & 15;  // col chunk

  const int cnt = counts[m];
  const int start = fillpos[m] - cnt;

  const float4* kp = (const float4*)(keys_proj + (size_t)m * D);
  const float4 k1 = kp[2 * t], k2 = kp[2 * t + 1];
  const float4* vr = (const float4*)values;

  float run_m = -FLT_MAX, run_l = 0.0f;
  float4 accA = {0, 0, 0, 0}, accB = {0, 0, 0, 0};

  float4 a = {0, 0, 0, 0}, b = {0, 0, 0, 0};
  if (cnt > 0) {
    int id = rowids[start + min(g, cnt - 1)];
    a = vr[(size_t)id * 32 + 2 * t];
    b = vr[(size_t)id * 32 + 2 * t + 1];
  }

  for (int gb = 0; gb < cnt; gb += 4) {
    const float4 ca = a, cb = b;
    if (gb + 4 < cnt) {  // prefetch next group
      int nid = rowids[start + min(gb + 4 + g, cnt - 1)];
      a = vr[(size_t)nid * 32 + 2 * t];
      b = vr[(size_t)nid * 32 + 2 * t + 1];
    }
    float s = ca.x * k1.x + ca.y * k1.y + ca.z * k1.z + ca.w * k1.w +
              cb.x * k2.x + cb.y * k2.y + cb.z * k2.z + cb.w * k2.w;
    s += __shfl_xor(s, 1, 64);
    s += __shfl_xor(s, 2, 64);
    s += __shfl_xor(s, 4, 64);
    s += __shfl_xor(s, 8, 64);
    const float s0 = __shfl(s, 0, 64);
    const float s1 = __shfl(s, 16, 64);
    const float s2 = __shfl(s, 32, 64);
    const float s3 = __shfl(s, 48, 64);

    float al0, al1, al2, al3, p0, p1, p2, p3;
#define STEP(sj, actj, alj, pj)                                   \
    {                                                             \
      float ss = (actj) ? (sj) : -FLT_MAX;                        \
      float mn = fmaxf(run_m, ss);                                \
      alj = __expf(run_m - mn);                                   \
      pj = (actj) ? __expf(ss - mn) : 0.0f;                       \
      run_l = run_l * alj + pj;                                   \
      run_m = mn;                                                 \
    }
    STEP(s0, true, al0, p0);
    STEP(s1, gb + 1 < cnt, al1, p1);
    STEP(s2, gb + 2 < cnt, al2, p2);
    STEP(s3, gb + 3 < cnt, al3, p3);
#undef STEP
    const float f3 = 1.0f;
    const float f2 = al3;
    const float f1 = al3 * al2;
    const float f0 = f1 * al1;
    const float scale = f0 * al0;
    const float w = (g == 0) ? p0 * f0 : (g == 1) ? p1 * f1
                  : (g == 2) ? p2 * f2 : p3 * f3;
    accA.x = accA.x * scale + ca.x * w;
    accA.y = accA.y * scale + ca.y * w;
    accA.z = accA.z * scale + ca.z * w;
    accA.w = accA.w * scale + ca.w * w;
    accB.x = accB.x * scale + cb.x * w;
    accB.y = accB.y * scale + cb.y * w;
    accB.z = accB.z * scale + cb.z * w;
    accB.w = accB.w * scale + cb.w * w;

    if (lane == 0) {
      int r = gb;
      if (r < cnt) { if (r < CAP) sS[wv][r] = s0; else raw_ovf[start + r] = s0; }
      r = gb + 1;
      if (r < cnt) { if (r < CAP) sS[wv][r] = s1; else raw_ovf[start + r] = s1; }
      r = gb + 2;
      if (r < cnt) { if (r < CAP) sS[wv][r] = s2; else raw_ovf[start + r] = s2; }
      r = gb + 3;
      if (r < cnt) { if (r < CAP) sS[wv][r] = s3; else raw_ovf[start + r] = s3; }
    }
  }

  // combine acc across the 4 row slots (xor 16, 32)
#define RED(x) x += __shfl_xor(x, 16, 64); x += __shfl_xor(x, 32, 64)
  RED(accA.x); RED(accA.y); RED(accA.z); RED(accA.w);
  RED(accB.x); RED(accB.y); RED(accB.z); RED(accB.w);
#undef RED

  const float invl = (run_l > 0.0f) ? 1.0f / run_l : 0.0f;
  if (g == 0) {
    float4* op = (float4*)(attn_out + (size_t)m * D);
    float4 oA = {accA.x * invl, accA.y * invl, accA.z * invl, accA.w * invl};
    float4 oB = {accB.x * invl, accB.y * invl, accB.z * invl, accB.w * invl};
    op[2 * t] = oA;
    op[2 * t + 1] = oB;
  }

  // finalize scores: lane-parallel over the segment's rows
  for (int r = lane; r < cnt; r += 64) {
    const float s = (r < CAP) ? sS[wv][r] : raw_ovf[start + r];
    const int i = rowids[start + r];
    scores[i] = __expf(s - run_m) * invl;
  }
}

extern "C" void kernel_launch(void* const* d_in, const int* in_sizes, int n_in,
                              void* d_out, int out_size, void* d_ws, size_t ws_size,
                              hipStream_t stream) {
  const float* values = (const float*)d_in[0];
  const int* indices = (const int*)d_in[1];
  const float* attn_keys = (const float*)d_in[2];
  const float* W = (const float*)d_in[3];
  const float* b = (const float*)d_in[4];
  const int N = in_sizes[0] / D;  // 1,000,000
  const int M = in_sizes[2] / D;  // 50,000

  // ws: keys_proj [M*D] | counts [M] | fillpos [M] | cursor [64] | rowids [N] | raw_ovf [N]
  float* keys_proj = (float*)d_ws;
  int* counts = (int*)(keys_proj + (size_t)M * D);
  int* fillpos = counts + M;
  int* cursor = fillpos + M;
  int* rowids = cursor + 64;
  float* raw_ovf = (float*)(rowids + N);

  float* scores = (float*)d_out;
  float* attn_out = scores + N;

  hipMemsetAsync(counts, 0, (size_t)M * sizeof(int), stream);
  hipMemsetAsync(cursor, 0, 64 * sizeof(int), stream);

  k_keys_proj<<<(M + 31) / 32, 256, 0, stream>>>(attn_keys, W, b, keys_proj, M);
  k_count<<<1024, 256, 0, stream>>>(indices, counts, N);
  k_offsets<<<(M + 255) / 256, 256, 0, stream>>>(counts, fillpos, cursor, M);
  k_fill<<<1024, 256, 0, stream>>>(indices, fillpos, rowids, N);
  k_segment<<<(M + 3) / 4, 256, 0, stream>>>(values, rowids, counts, fillpos,
                                             keys_proj, raw_ovf, scores, attn_out, M);
}